// Round 7
// baseline (324.989 us; speedup 1.0000x reference)
//
#include <hip/hip_runtime.h>
#include <hip/hip_bf16.h>

typedef __bf16 bf16_t;
typedef __bf16 bf16x8 __attribute__((ext_vector_type(8)));
typedef float f32x4 __attribute__((ext_vector_type(4)));
typedef _Float16 f16_t;
typedef _Float16 f16x4 __attribute__((ext_vector_type(4)));

#define DEVI static __device__ __forceinline__

static constexpr int TN   = 2048;   // T
static constexpr int Hn   = 1024;   // H
static constexpr int Rn   = 256;    // R
static constexpr int MTOK = 4096;   // B*T
static constexpr int NCAT = 6144;   // 6*H  (lr q,k,v | full q,k,v)

static constexpr float QSCALE = 0.125f;          // 1/sqrt(DH), folded into W_q/b_q
// scaled fixed-offset softmax: P' = exp(s-10)*2^14 (f16-normal for |s|<~9)
static constexpr float SOFT_OFF = 0.2959399f;    // 10 - 14*ln(2)

// ---------- async global->LDS (16B per lane; LDS dest = wave base + lane*16) ----------
template <typename T>
DEVI void gload16(const T* g, T* l) {
    __builtin_amdgcn_global_load_lds(
        (const __attribute__((address_space(1))) void*)g,
        (__attribute__((address_space(3))) void*)l, 16, 0, 0);
}

// ---------- dual-dtype input read (f32 or bf16 storage, per-thread detect) ----------
DEVI float loadf(const void* base, int idx, bool bfm) {
    if (bfm) {
        unsigned int u = ((const unsigned short*)base)[idx];
        u <<= 16;
        return __builtin_bit_cast(float, u);
    }
    return ((const float*)base)[idx];
}
// mask[0,0] is exactly 0.0f in f32 storage; ~-1e9-bits if really bf16-packed.
DEVI bool detect_bf16(const void* mask) {
    return fabsf(((const float*)mask)[0]) > 1.0f;
}

// ---------- fused prep: x->bf16, lowrank factor prep, bias concat ----------
struct PrepArgs {
    const void *x, *mask;
    const void *Vh[4], *S[4], *U[4];
    const void *bb[4], *bfb[4];
    bf16_t *Xb, *Abuf, *Bbuf;
    float *biascat, *biaso;
};

__global__ void k_prep(PrepArgs a) {
    const bool bfm = detect_bf16(a.mask);
    const int bid = blockIdx.x;
    if (bid < 4096) {                       // x -> bf16 (4 elems/thread)
        int i = (bid * 256 + threadIdx.x) * 4;
#pragma unroll
        for (int j = 0; j < 4; ++j) a.Xb[i + j] = (bf16_t)loadf(a.x, i + j, bfm);
    } else if (bid < 8192) {                // A = U*S (q*1/8, o*0.6), B = Vh
        int idx = (bid - 4096) * 256 + threadIdx.x;
        int proj = idx >> 18;
        int e = idx & 262143;
        int r = e & 255;
        float s = loadf(a.S[proj], r, bfm);
        if (proj == 0) s *= QSCALE;
        if (proj == 3) s *= 0.6f;
        a.Abuf[idx] = (bf16_t)(loadf(a.U[proj], e, bfm) * s);
        a.Bbuf[idx] = (bf16_t)loadf(a.Vh[proj], e, bfm);
    } else {                                // bias concat (28 blocks)
        int i = (bid - 8192) * 256 + threadIdx.x;
        if (i < 1024)      a.biascat[i] = QSCALE * loadf(a.bb[0], i, bfm);
        else if (i < 2048) a.biascat[i] = loadf(a.bb[1], i - 1024, bfm);
        else if (i < 3072) a.biascat[i] = loadf(a.bb[2], i - 2048, bfm);
        else if (i < 4096) a.biascat[i] = QSCALE * loadf(a.bfb[0], i - 3072, bfm);
        else if (i < 5120) a.biascat[i] = loadf(a.bfb[1], i - 4096, bfm);
        else if (i < 6144) a.biascat[i] = loadf(a.bfb[2], i - 5120, bfm);
        else {
            int j = i - 6144;
            a.biaso[j] = 0.6f * loadf(a.bb[3], j, bfm) + 0.4f * loadf(a.bfb[3], j, bfm);
        }
    }
}

// ---------- fused full-rank weight transposes (W[i][j] -> dst[j][i]*scale) ----------
struct TransP { const void* W[4]; bf16_t* dst[4]; int ldd[4]; float scale[4]; const void* mask; };

__global__ void k_transpose4(TransP tp) {
    const bool bfm = detect_bf16(tp.mask);
    const int z = blockIdx.z;
    const void* W = tp.W[z];
    bf16_t* dst = tp.dst[z];
    const int ldd = tp.ldd[z];
    const float scale = tp.scale[z];
    __shared__ float t[32][33];
    int bx = blockIdx.x * 32, by = blockIdx.y * 32;
    int tx = threadIdx.x, ty = threadIdx.y;     // block (32,8)
#pragma unroll
    for (int k = 0; k < 32; k += 8)
        t[ty + k][tx] = loadf(W, (by + ty + k) * Hn + bx + tx, bfm);
    __syncthreads();
#pragma unroll
    for (int k = 0; k < 32; k += 8)
        dst[(size_t)(bx + ty + k) * ldd + by + tx] = (bf16_t)(scale * t[tx][ty + k]);
}

// ---------- double-buffered BK=32 GEMM core (flash6-style single barrier) ----------
template <int MI>
DEVI void gemm_stage(const bf16_t* __restrict__ A, int lda,
                     const bf16_t* __restrict__ B, int ldb,
                     int bm, int bn, int kb, bf16_t* Ad, bf16_t* Bd) {
    const int tid = threadIdx.x;
    constexpr int MT = MI * 32;
#pragma unroll
    for (int u = tid; u < MT * 4; u += 256)
        gload16(&A[(size_t)(bm + (u >> 2)) * lda + kb + (u & 3) * 8], &Ad[u * 8]);
#pragma unroll
    for (int u = tid; u < 512; u += 256)
        gload16(&B[(size_t)(bn + (u >> 2)) * ldb + kb + (u & 3) * 8], &Bd[u * 8]);
}

// barrier -> prefetch(kb+1) into alt buffer -> compute(kb). The barrier's
// vmcnt(0) drain waits on a DMA that had a full compute phase to complete.
template <int MI>
DEVI void gemm_core_db(const bf16_t* __restrict__ A, int lda,
                       const bf16_t* __restrict__ B, int ldb, int K,
                       bf16_t* Ab0, bf16_t* Ab1, bf16_t* Bb0, bf16_t* Bb1,
                       int bm, int bn, f32x4 (&acc)[MI][4]) {
    const int lane = threadIdx.x & 63;
    const int w    = threadIdx.x >> 6;
    const int wr   = (w >> 1) * (MI * 16);
    const int wc   = (w & 1) * 64;
    const int fr   = lane & 15;
    const int quad = lane >> 4;

#pragma unroll
    for (int i = 0; i < MI; ++i)
#pragma unroll
        for (int j = 0; j < 4; ++j) acc[i][j] = {0.f, 0.f, 0.f, 0.f};

    gemm_stage<MI>(A, lda, B, ldb, bm, bn, 0, Ab0, Bb0);

    const int nk = K >> 5;
    for (int kb = 0; kb < nk; ++kb) {
        const bf16_t* Ac = (kb & 1) ? Ab1 : Ab0;
        const bf16_t* Bc = (kb & 1) ? Bb1 : Bb0;
        __syncthreads();
        if (kb + 1 < nk)
            gemm_stage<MI>(A, lda, B, ldb, bm, bn, (kb + 1) * 32,
                           (kb & 1) ? Ab0 : Ab1, (kb & 1) ? Bb0 : Bb1);
        bf16x8 af[MI], bfv[4];
#pragma unroll
        for (int i = 0; i < MI; ++i)
            af[i] = *(const bf16x8*)&Ac[(wr + i * 16 + fr) * 32 + quad * 8];
#pragma unroll
        for (int j = 0; j < 4; ++j)
            bfv[j] = *(const bf16x8*)&Bc[(wc + j * 16 + fr) * 32 + quad * 8];
#pragma unroll
        for (int i = 0; i < MI; ++i)
#pragma unroll
            for (int j = 0; j < 4; ++j)
                acc[i][j] = __builtin_amdgcn_mfma_f32_16x16x32_bf16(af[i], bfv[j], acc[i][j], 0, 0, 0);
    }
}

// ---------- main GEMM: C[M,N] = A[M,K] @ B[N,K]^T + bias ----------
// SWZ: 0 = 2D grid; 1 = QKV XCD swizzle (xcd owns 6 bn cols); 2 = out-proj
// XCD swizzle (xcd owns 8 bm rows). WRITE_VT: V-col blocks -> f16 V^T.
template <int MI, bool OUT_DUAL, bool WRITE_VT, int SWZ>
__global__ __launch_bounds__(256)
void k_gemm(const bf16_t* __restrict__ A, int lda,
            const bf16_t* __restrict__ B, int ldb,
            void* __restrict__ C, int ldc, int K,
            const float* __restrict__ bias, const void* __restrict__ mask,
            f16_t* __restrict__ Vt_g) {
    constexpr int MT = MI * 32;
    struct GB { bf16_t A0[MT * 32]; bf16_t A1[MT * 32]; bf16_t B0[4096]; bf16_t B1[4096]; };
    union SM { GB g; f16_t Ls[WRITE_VT ? 128 * 136 : 8]; };
    __shared__ __align__(16) SM sm;

    int bm, bn;
    if constexpr (SWZ == 1) {          // 1536 blocks: xcd=id&7 owns bn in [xcd*6, xcd*6+6)
        const int id = blockIdx.x, xcd = id & 7, idx = id >> 3;
        bn = (xcd * 6 + idx % 6) * 128;
        bm = (idx / 6) * MT;
    } else if constexpr (SWZ == 2) {   // 512 blocks: xcd owns bm in [xcd*8, xcd*8+8)
        const int id = blockIdx.x, xcd = id & 7, idx = id >> 3;
        bm = (xcd * 8 + (idx & 7)) * MT;
        bn = (idx >> 3) * 128;
    } else {
        bm = blockIdx.x * MT;
        bn = blockIdx.y * 128;
    }

    const int tid  = threadIdx.x;
    const int lane = tid & 63;
    const int w    = tid >> 6;
    const int wr   = (w >> 1) * (MI * 16);
    const int wc   = (w & 1) * 64;
    const int fr   = lane & 15;
    const int quad = lane >> 4;

    f32x4 acc[MI][4];
    gemm_core_db<MI>(A, lda, B, ldb, K, sm.g.A0, sm.g.A1, sm.g.B0, sm.g.B1, bm, bn, acc);

    if constexpr (WRITE_VT) {
        const bool isV = (bn >= 2048 && bn < 3072) || (bn >= 5120);
        if (isV) {
            const int pth = (bn >= 5120) ? 1 : 0;
            const int colrel = bn - (pth ? 5120 : 2048);
            const int bb = bm >> 11;
            const int R0 = (pth * 32 + bb * 16 + (colrel >> 6)) * 64;
            const int tloc = bm & 2047;
            __syncthreads();                 // done reading A/B panels
#pragma unroll
            for (int i = 0; i < MI; ++i) {
                const int t0 = wr + i * 16 + quad * 4;
#pragma unroll
                for (int j = 0; j < 4; ++j) {
                    const int c = wc + j * 16 + fr;
                    const float bv = bias[bn + c];
#pragma unroll
                    for (int r = 0; r < 4; ++r)
                        sm.Ls[c * 136 + t0 + r] = (f16_t)(acc[i][j][r] + bv);
                }
            }
            __syncthreads();
            const int c = tid >> 1, seg = tid & 1;
            f16_t* dst = &Vt_g[(size_t)(R0 + c) * TN + tloc + seg * 64];
            const f16_t* src = &sm.Ls[c * 136 + seg * 64];
#pragma unroll
            for (int e = 0; e < 8; ++e)
                *(uint4*)&dst[e * 8] = *(const uint4*)&src[e * 8];
            return;
        }
    }

    bool bfm = false;
    if constexpr (OUT_DUAL) bfm = detect_bf16(mask);
#pragma unroll
    for (int i = 0; i < MI; ++i) {
        const int row0 = bm + wr + i * 16 + quad * 4;
#pragma unroll
        for (int j = 0; j < 4; ++j) {
            const int col = bn + wc + j * 16 + fr;
            const float bv = bias ? bias[col] : 0.f;
#pragma unroll
            for (int r = 0; r < 4; ++r) {
                float v = acc[i][j][r] + bv;
                size_t ci = (size_t)(row0 + r) * ldc + col;
                if constexpr (OUT_DUAL) {
                    if (bfm) ((unsigned short*)C)[ci] = __builtin_bit_cast(unsigned short, (bf16_t)v);
                    else     ((float*)C)[ci] = v;
                } else {
                    ((bf16_t*)C)[ci] = (bf16_t)v;
                }
            }
        }
    }
}

// ---------- fused 4x small GEMM (low-rank effective weights), z-indexed ----------
__global__ __launch_bounds__(256)
void k_gemm_small4(const bf16_t* __restrict__ Abuf, const bf16_t* __restrict__ Bbuf,
                   bf16_t* __restrict__ Wcat, bf16_t* __restrict__ WoT) {
    __shared__ __align__(16) bf16_t A0[64 * 32], A1[64 * 32], B0[4096], B1[4096];
    const int z = blockIdx.z;
    const bf16_t* A = Abuf + (size_t)z * Hn * Rn;
    const bf16_t* B = Bbuf + (size_t)z * Hn * Rn;
    bf16_t* C = (z < 3) ? (Wcat + (size_t)z * Hn * Hn) : WoT;
    const int ldc = (z < 3) ? Hn : 2048;

    const int bm = blockIdx.x * 64, bn = blockIdx.y * 128;
    f32x4 acc[2][4];
    gemm_core_db<2>(A, Rn, B, Rn, Rn, A0, A1, B0, B1, bm, bn, acc);

    const int lane = threadIdx.x & 63;
    const int w    = threadIdx.x >> 6;
    const int wr   = (w >> 1) * 32;
    const int wc   = (w & 1) * 64;
    const int fr   = lane & 15;
    const int quad = lane >> 4;
#pragma unroll
    for (int i = 0; i < 2; ++i)
#pragma unroll
        for (int j = 0; j < 4; ++j)
#pragma unroll
            for (int r = 0; r < 4; ++r)
                C[(size_t)(bm + wr + i * 16 + quad * 4 + r) * ldc + bn + wc + j * 16 + fr]
                    = (bf16_t)acc[i][j][r];
}

// ---------- causal flash attention v6: 64-key tiles, XCD-pinned, double-buffered ----------
__global__ __launch_bounds__(256, 4)
void k_flash6(const bf16_t* __restrict__ Y, const f16_t* __restrict__ Vt_g,
              bf16_t* __restrict__ Ctx) {
    const int id   = blockIdx.x;
    const int inst = id & 63;               // p*32 + b*16 + h
    const int qt2  = 15 - (id >> 6);        // longest q-tiles dispatched first
    const int p = inst >> 5, b = (inst >> 4) & 1, h = inst & 15;

    const int tid  = threadIdx.x;
    const int lane = tid & 63;
    const int w    = tid >> 6;
    const int fr   = lane & 15;
    const int quad = lane >> 4;

    const int rowbase = b * TN;
    const int qbase   = qt2 * 128;
    const int qcol = p * 3072 + h * 64;
    const int kcol = qcol + 1024;
    const int ccol = p * 1024 + h * 64;

    __shared__ __align__(16) bf16_t Kb[2][2][64 * 32];   // [buf][dh-half][key][32]
    __shared__ __align__(16) f16_t  Vb[2][64 * 64];      // [buf] V^T chunk-swizzled

    const int r64 = tid >> 2;
    const int c8  = (tid & 3) * 8;

    size_t vsrc[2];
#pragma unroll
    for (int t = 0; t < 2; ++t) {
        int pp = w * 128 + t * 64 + lane;
        int d  = pp >> 3;
        vsrc[t] = (size_t)(inst * 64 + d) * TN + ((((pp & 7) - d) & 7) * 8);
    }

    f16x4 ones;
#pragma unroll
    for (int j = 0; j < 4; ++j) ones[j] = (f16_t)1.0f;

    bf16x8 qf[2][2];
#pragma unroll
    for (int s = 0; s < 2; ++s) {
        const size_t qrow = (size_t)(rowbase + qbase + s * 64 + w * 16 + fr) * NCAT + qcol;
        qf[s][0] = *(const bf16x8*)&Y[qrow + quad * 8];
        qf[s][1] = *(const bf16x8*)&Y[qrow + 32 + quad * 8];
    }

    f32x4 o[2][4], lacc[2];
#pragma unroll
    for (int s = 0; s < 2; ++s) {
        lacc[s] = {0.f, 0.f, 0.f, 0.f};
#pragma unroll
        for (int db = 0; db < 4; ++db) o[s][db] = {0.f, 0.f, 0.f, 0.f};
    }

    const int t0 = (quad >> 1) + (fr & 7);   // V read swizzle base
    const int h4 = (quad & 1) * 4;           // 8B half within 16B chunk

    const int kmax = 2 * qt2 + 1;

    auto stage = [&](int kt, int bsel) {
        const bf16_t* ksrc = &Y[(size_t)(rowbase + kt * 64 + r64) * NCAT + kcol + c8];
        gload16(ksrc,      &Kb[bsel][0][tid * 8]);
        gload16(ksrc + 32, &Kb[bsel][1][tid * 8]);
#pragma unroll
        for (int t = 0; t < 2; ++t)
            gload16(&Vt_g[vsrc[t] + kt * 64], &Vb[bsel][(w * 128 + t * 64 + lane) * 8]);
    };

    stage(0, 0);

    for (int kt = 0; kt <= kmax; ++kt) {
        const int cur = kt & 1;
        __syncthreads();                       // drains DMA(kt); frees buf cur^1
        if (kt < kmax) stage(kt + 1, cur ^ 1); // prefetch overlaps compute below

#pragma unroll
        for (int s = 0; s < 2; ++s) {
            const int dk = 2 * qt2 + s;
            if (kt > dk) continue;

            f32x4 sacc[4];
#pragma unroll
            for (int nb = 0; nb < 4; ++nb) {
                bf16x8 kf0 = *(const bf16x8*)&Kb[cur][0][(nb * 16 + fr) * 32 + quad * 8];
                bf16x8 kf1 = *(const bf16x8*)&Kb[cur][1][(nb * 16 + fr) * 32 + quad * 8];
                f32x4 t4 = {0.f, 0.f, 0.f, 0.f};
                t4 = __builtin_amdgcn_mfma_f32_16x16x32_bf16(kf0, qf[s][0], t4, 0, 0, 0);
                t4 = __builtin_amdgcn_mfma_f32_16x16x32_bf16(kf1, qf[s][1], t4, 0, 0, 0);
                sacc[nb] = t4;
            }
            if (kt == dk) {
                const int kl = quad * 4;
                const int ql = w * 16 + fr;
#pragma unroll
                for (int nb = 0; nb < 4; ++nb)
#pragma unroll
                    for (int r = 0; r < 4; ++r)
                        if (nb * 16 + kl + r > ql) sacc[nb][r] = -1e30f;
            }

            f16x4 pf[4];
#pragma unroll
            for (int nb = 0; nb < 4; ++nb)
#pragma unroll
                for (int r = 0; r < 4; ++r)
                    pf[nb][r] = (f16_t)__expf(sacc[nb][r] - SOFT_OFF);

#pragma unroll
            for (int nb = 0; nb < 4; ++nb)
                lacc[s] = __builtin_amdgcn_mfma_f32_16x16x16f16(pf[nb], ones, lacc[s], 0, 0, 0);

#pragma unroll
            for (int db = 0; db < 4; ++db) {
                const int vbase = (db * 16 + fr) * 64 + h4;
#pragma unroll
                for (int nb = 0; nb < 4; ++nb) {
                    f16x4 vf = *(const f16x4*)&Vb[cur][vbase + (((nb * 2 + t0) & 7) * 8)];
                    o[s][db] = __builtin_amdgcn_mfma_f32_16x16x16f16(pf[nb], vf, o[s][db], 0, 0, 0);
                }
            }
        }
    }

#pragma unroll
    for (int s = 0; s < 2; ++s)
#pragma unroll
        for (int r = 0; r < 4; ++r) {
            const float inv = 1.0f / lacc[s][r];
            const size_t trow = (size_t)(rowbase + qbase + s * 64 + w * 16 + quad * 4 + r);
#pragma unroll
            for (int db = 0; db < 4; ++db)
                Ctx[trow * 2048 + ccol + db * 16 + fr] = (bf16_t)(o[s][db][r] * inv);
        }
}

// ---------- launcher ----------
extern "C" void kernel_launch(void* const* d_in, const int* in_sizes, int n_in,
                              void* d_out, int out_size, void* d_ws, size_t ws_size,
                              hipStream_t stream) {
    const void* x    = d_in[0];
    const void* mask = d_in[1];
    const void* Vh[4] = { d_in[2],  d_in[6],  d_in[10], d_in[14] };
    const void* Sp[4] = { d_in[3],  d_in[7],  d_in[11], d_in[15] };
    const void* Up[4] = { d_in[4],  d_in[8],  d_in[12], d_in[16] };
    const void* bb[4] = { d_in[5],  d_in[9],  d_in[13], d_in[17] };
    const void* Wp[4] = { d_in[18], d_in[20], d_in[22], d_in[24] };
    const void* bf[4] = { d_in[19], d_in[21], d_in[23], d_in[25] };

    char* ws = (char*)d_ws;
    size_t off = 0;
    auto alloc = [&](size_t bytes) -> void* {
        void* p = ws + off;
        off = (off + bytes + 255) & ~(size_t)255;
        return p;
    };
    bf16_t* Xb      = (bf16_t*)alloc((size_t)MTOK * Hn * 2);       // 8 MB
    bf16_t* Wcat    = (bf16_t*)alloc((size_t)NCAT * Hn * 2);       // 12 MB  [N=6144][K=1024]
    bf16_t* Yb      = (bf16_t*)alloc((size_t)MTOK * NCAT * 2);     // 48 MB  (V cols unused)
    bf16_t* Ctx     = (bf16_t*)alloc((size_t)MTOK * 2048 * 2);     // 16 MB  [tok][lr|full]
    bf16_t* WoT     = (bf16_t*)alloc((size_t)Hn * 2048 * 2);       // 4 MB   [N=1024][K=2048]
    f16_t*  Vt_g    = (f16_t*)alloc((size_t)64 * 64 * TN * 2);     // 16 MB  [inst*64+d][key] f16
    bf16_t* Abuf    = (bf16_t*)alloc((size_t)4 * Hn * Rn * 2);
    bf16_t* Bbuf    = (bf16_t*)alloc((size_t)4 * Hn * Rn * 2);
    float*  biascat = (float*)alloc(NCAT * 4);
    float*  biaso   = (float*)alloc(Hn * 4);

    // 1) fused prep (x convert + lowrank factors + biases)
    PrepArgs pa;
    pa.x = x; pa.mask = mask;
    for (int i = 0; i < 4; ++i) {
        pa.Vh[i] = Vh[i]; pa.S[i] = Sp[i]; pa.U[i] = Up[i];
        pa.bb[i] = bb[i]; pa.bfb[i] = bf[i];
    }
    pa.Xb = Xb; pa.Abuf = Abuf; pa.Bbuf = Bbuf; pa.biascat = biascat; pa.biaso = biaso;
    k_prep<<<8220, 256, 0, stream>>>(pa);

    // 2) fused full-rank transposes (q scaled 1/8, o scaled 0.4)
    TransP tp;
    for (int i = 0; i < 3; ++i) {
        tp.W[i] = Wp[i]; tp.dst[i] = Wcat + (size_t)(3 * Hn + i * Hn) * Hn;
        tp.ldd[i] = Hn; tp.scale[i] = (i == 0) ? QSCALE : 1.0f;
    }
    tp.W[3] = Wp[3]; tp.dst[3] = WoT + 1024; tp.ldd[3] = 2048; tp.scale[3] = 0.4f;
    tp.mask = mask;
    k_transpose4<<<dim3(32, 32, 4), dim3(32, 8), 0, stream>>>(tp);

    // 3) low-rank effective weights: Wlr^T = (U*S) @ Vh^T
    k_gemm_small4<<<dim3(16, 8, 4), 256, 0, stream>>>(Abuf, Bbuf, Wcat, WoT);

    // 4) fused QKV (both paths): Y = x @ Wcat^T + biascat; V-blocks -> Vt_g (f16)
    //    XCD-swizzled 1D grid: each XCD owns 6 bn columns (B slice resident in L2)
    k_gemm<4, false, true, 1><<<1536, 256, 0, stream>>>(
        Xb, Hn, Wcat, Hn, Yb, NCAT, Hn, biascat, nullptr, Vt_g);

    // 5) causal flash attention, both paths (XCD-pinned 1D grid)
    k_flash6<<<1024, 256, 0, stream>>>(Yb, Vt_g, Ctx);

    // 6) fused output projection + ALPHA blend; xcd owns 8 bm rows (A+B ~ L2)
    k_gemm<2, true, false, 2><<<512, 256, 0, stream>>>(
        Ctx, 2048, WoT, 2048, d_out, Hn, 2048, biaso, mask, nullptr);
}

// Round 8
// 320.404 us; speedup vs baseline: 1.0143x; 1.0143x over previous
//
#include <hip/hip_runtime.h>
#include <hip/hip_bf16.h>

typedef __bf16 bf16_t;
typedef __bf16 bf16x8 __attribute__((ext_vector_type(8)));
typedef float f32x4 __attribute__((ext_vector_type(4)));
typedef _Float16 f16_t;
typedef _Float16 f16x4 __attribute__((ext_vector_type(4)));

#define DEVI static __device__ __forceinline__

static constexpr int TN   = 2048;   // T
static constexpr int Hn   = 1024;   // H
static constexpr int Rn   = 256;    // R
static constexpr int MTOK = 4096;   // B*T
static constexpr int NCAT = 6144;   // 6*H  (lr q,k,v | full q,k,v)

static constexpr float QSCALE = 0.125f;          // 1/sqrt(DH), folded into W_q/b_q
// scaled fixed-offset softmax: P' = exp(s-10)*2^14 (f16-normal for |s|<~9)
static constexpr float SOFT_OFF = 0.2959399f;    // 10 - 14*ln(2)

// ---------- async global->LDS (16B per lane; LDS dest = wave base + lane*16) ----------
template <typename T>
DEVI void gload16(const T* g, T* l) {
    __builtin_amdgcn_global_load_lds(
        (const __attribute__((address_space(1))) void*)g,
        (__attribute__((address_space(3))) void*)l, 16, 0, 0);
}

// ---------- dual-dtype input read (f32 or bf16 storage, per-thread detect) ----------
DEVI float loadf(const void* base, int idx, bool bfm) {
    if (bfm) {
        unsigned int u = ((const unsigned short*)base)[idx];
        u <<= 16;
        return __builtin_bit_cast(float, u);
    }
    return ((const float*)base)[idx];
}
// mask[0,0] is exactly 0.0f in f32 storage; ~-1e9-bits if really bf16-packed.
DEVI bool detect_bf16(const void* mask) {
    return fabsf(((const float*)mask)[0]) > 1.0f;
}

// ---------- fused prep: x->bf16, lowrank factors, biases, weight transposes ----------
struct PrepArgs {
    const void *x, *mask;
    const void *Vh[4], *S[4], *U[4];
    const void *bb[4], *bfb[4];
    const void *W[4];
    bf16_t *Wdst[4]; int Wldd[4]; float Wscale[4];
    bf16_t *Xb, *Abuf, *Bbuf;
    float *biascat, *biaso;
};

__global__ void k_prep(PrepArgs a) {
    const bool bfm = detect_bf16(a.mask);
    const int bid = blockIdx.x;
    const int tid = threadIdx.x;
    __shared__ float t[32][33];
    if (bid < 4096) {                       // x -> bf16 (4 elems/thread)
        int i = (bid * 256 + tid) * 4;
#pragma unroll
        for (int j = 0; j < 4; ++j) a.Xb[i + j] = (bf16_t)loadf(a.x, i + j, bfm);
    } else if (bid < 8192) {                // A = U*S (q*1/8, o*0.6), B = Vh
        int idx = (bid - 4096) * 256 + tid;
        int proj = idx >> 18;
        int e = idx & 262143;
        int r = e & 255;
        float s = loadf(a.S[proj], r, bfm);
        if (proj == 0) s *= QSCALE;
        if (proj == 3) s *= 0.6f;
        a.Abuf[idx] = (bf16_t)(loadf(a.U[proj], e, bfm) * s);
        a.Bbuf[idx] = (bf16_t)loadf(a.Vh[proj], e, bfm);
    } else if (bid < 8220) {                // bias concat (28 blocks)
        int i = (bid - 8192) * 256 + tid;
        if (i < 1024)      a.biascat[i] = QSCALE * loadf(a.bb[0], i, bfm);
        else if (i < 2048) a.biascat[i] = loadf(a.bb[1], i - 1024, bfm);
        else if (i < 3072) a.biascat[i] = loadf(a.bb[2], i - 2048, bfm);
        else if (i < 4096) a.biascat[i] = QSCALE * loadf(a.bfb[0], i - 3072, bfm);
        else if (i < 5120) a.biascat[i] = loadf(a.bfb[1], i - 4096, bfm);
        else if (i < 6144) a.biascat[i] = loadf(a.bfb[2], i - 5120, bfm);
        else {
            int j = i - 6144;
            a.biaso[j] = 0.6f * loadf(a.bb[3], j, bfm) + 0.4f * loadf(a.bfb[3], j, bfm);
        }
    } else {                                // 4x weight transpose (4096 blocks)
        const int tb = bid - 8220;
        const int z = tb >> 10;
        const int t2 = tb & 1023;
        const int bx = (t2 & 31) * 32, by = (t2 >> 5) * 32;
        const int tx = tid & 31, ty = tid >> 5;     // 32x8
        const void* W = a.W[z];
        bf16_t* dst = a.Wdst[z];
        const int ldd = a.Wldd[z];
        const float scale = a.Wscale[z];
#pragma unroll
        for (int k = 0; k < 32; k += 8)
            t[ty + k][tx] = loadf(W, (by + ty + k) * Hn + bx + tx, bfm);
        __syncthreads();
#pragma unroll
        for (int k = 0; k < 32; k += 8)
            dst[(size_t)(bx + ty + k) * ldd + by + tx] = (bf16_t)(scale * t[tx][ty + k]);
    }
}

// ---------- double-buffered BK=32 GEMM core (single barrier per k-step) ----------
template <int MI>
DEVI void gemm_stage(const bf16_t* __restrict__ A, int lda,
                     const bf16_t* __restrict__ B, int ldb,
                     int bm, int bn, int kb, bf16_t* Ad, bf16_t* Bd) {
    const int tid = threadIdx.x;
    constexpr int MT = MI * 32;
#pragma unroll
    for (int u = tid; u < MT * 4; u += 256)
        gload16(&A[(size_t)(bm + (u >> 2)) * lda + kb + (u & 3) * 8], &Ad[u * 8]);
#pragma unroll
    for (int u = tid; u < 512; u += 256)
        gload16(&B[(size_t)(bn + (u >> 2)) * ldb + kb + (u & 3) * 8], &Bd[u * 8]);
}

// barrier -> prefetch(kb+1) into alt buffer -> compute(kb). The barrier's
// vmcnt(0) drain waits on a DMA that had a full compute phase to complete.
template <int MI>
DEVI void gemm_core_db(const bf16_t* __restrict__ A, int lda,
                       const bf16_t* __restrict__ B, int ldb, int K,
                       bf16_t* Ab0, bf16_t* Ab1, bf16_t* Bb0, bf16_t* Bb1,
                       int bm, int bn, f32x4 (&acc)[MI][4]) {
    const int lane = threadIdx.x & 63;
    const int w    = threadIdx.x >> 6;
    const int wr   = (w >> 1) * (MI * 16);
    const int wc   = (w & 1) * 64;
    const int fr   = lane & 15;
    const int quad = lane >> 4;

#pragma unroll
    for (int i = 0; i < MI; ++i)
#pragma unroll
        for (int j = 0; j < 4; ++j) acc[i][j] = {0.f, 0.f, 0.f, 0.f};

    gemm_stage<MI>(A, lda, B, ldb, bm, bn, 0, Ab0, Bb0);

    const int nk = K >> 5;
    for (int kb = 0; kb < nk; ++kb) {
        const bf16_t* Ac = (kb & 1) ? Ab1 : Ab0;
        const bf16_t* Bc = (kb & 1) ? Bb1 : Bb0;
        __syncthreads();
        if (kb + 1 < nk)
            gemm_stage<MI>(A, lda, B, ldb, bm, bn, (kb + 1) * 32,
                           (kb & 1) ? Ab0 : Ab1, (kb & 1) ? Bb0 : Bb1);
        bf16x8 af[MI], bfv[4];
#pragma unroll
        for (int i = 0; i < MI; ++i)
            af[i] = *(const bf16x8*)&Ac[(wr + i * 16 + fr) * 32 + quad * 8];
#pragma unroll
        for (int j = 0; j < 4; ++j)
            bfv[j] = *(const bf16x8*)&Bc[(wc + j * 16 + fr) * 32 + quad * 8];
#pragma unroll
        for (int i = 0; i < MI; ++i)
#pragma unroll
            for (int j = 0; j < 4; ++j)
                acc[i][j] = __builtin_amdgcn_mfma_f32_16x16x32_bf16(af[i], bfv[j], acc[i][j], 0, 0, 0);
    }
}

// ---------- main GEMM: C[M,N] = A[M,K] @ B[N,K]^T (+ bias) ----------
// OMODE: 0 = bf16 C; 2 = f32 partial (split-K, no bias).
// SWZ: 1 = QKV XCD swizzle (xcd owns 6 bn cols); 3 = split-K out-proj
// (512 blocks: ksel=id>>8, xcd owns one 128-col bn slice of B).
// WRITE_VT (QKV only): V-column blocks write f16 V^T to Vt_g instead of C.
template <int MI, int OMODE, bool WRITE_VT, int SWZ>
__global__ __launch_bounds__(256)
void k_gemm(const bf16_t* __restrict__ A, int lda,
            const bf16_t* __restrict__ B, int ldb,
            void* __restrict__ C, int ldc, int K,
            const float* __restrict__ bias, f16_t* __restrict__ Vt_g) {
    constexpr int MT = MI * 32;
    struct GB { bf16_t A0[MT * 32]; bf16_t A1[MT * 32]; bf16_t B0[4096]; bf16_t B1[4096]; };
    union SM { GB g; f16_t Ls[WRITE_VT ? 128 * 136 : 8]; };
    __shared__ __align__(16) SM sm;

    int bm, bn;
    if constexpr (SWZ == 1) {          // 1536 blocks: xcd=id&7 owns bn in [xcd*6, xcd*6+6)
        const int id = blockIdx.x, xcd = id & 7, idx = id >> 3;
        bn = (xcd * 6 + idx % 6) * 128;
        bm = (idx / 6) * MT;
    } else if constexpr (SWZ == 3) {   // split-K: 512 blocks
        const int id = blockIdx.x;
        const int ksel = id >> 8;
        const int idx  = id & 255;
        bn = (idx & 7) * 128;          // xcd owns one B column slice (L2-resident)
        bm = (idx >> 3) * MT;
        A += ksel * 1024;              // K-half column offset (A and B)
        B += ksel * 1024;
        C = (void*)((float*)C + (size_t)ksel * MTOK * 1024);
    } else {
        bm = blockIdx.x * MT;
        bn = blockIdx.y * 128;
    }

    const int tid  = threadIdx.x;
    const int lane = tid & 63;
    const int w    = tid >> 6;
    const int wr   = (w >> 1) * (MI * 16);
    const int wc   = (w & 1) * 64;
    const int fr   = lane & 15;
    const int quad = lane >> 4;

    f32x4 acc[MI][4];
    gemm_core_db<MI>(A, lda, B, ldb, K, sm.g.A0, sm.g.A1, sm.g.B0, sm.g.B1, bm, bn, acc);

    if constexpr (WRITE_VT) {
        const bool isV = (bn >= 2048 && bn < 3072) || (bn >= 5120);
        if (isV) {
            const int pth = (bn >= 5120) ? 1 : 0;
            const int colrel = bn - (pth ? 5120 : 2048);
            const int bb = bm >> 11;
            const int R0 = (pth * 32 + bb * 16 + (colrel >> 6)) * 64;
            const int tloc = bm & 2047;
            __syncthreads();                 // done reading A/B panels
#pragma unroll
            for (int i = 0; i < MI; ++i) {
                const int t0 = wr + i * 16 + quad * 4;
#pragma unroll
                for (int j = 0; j < 4; ++j) {
                    const int c = wc + j * 16 + fr;
                    const float bv = bias[bn + c];
#pragma unroll
                    for (int r = 0; r < 4; ++r)
                        sm.Ls[c * 136 + t0 + r] = (f16_t)(acc[i][j][r] + bv);
                }
            }
            __syncthreads();
            const int c = tid >> 1, seg = tid & 1;
            f16_t* dst = &Vt_g[(size_t)(R0 + c) * TN + tloc + seg * 64];
            const f16_t* src = &sm.Ls[c * 136 + seg * 64];
#pragma unroll
            for (int e = 0; e < 8; ++e)
                *(uint4*)&dst[e * 8] = *(const uint4*)&src[e * 8];
            return;
        }
    }

#pragma unroll
    for (int i = 0; i < MI; ++i) {
        const int row0 = bm + wr + i * 16 + quad * 4;
#pragma unroll
        for (int j = 0; j < 4; ++j) {
            const int col = bn + wc + j * 16 + fr;
            const float bv = (OMODE == 0 && bias) ? bias[col] : 0.f;
#pragma unroll
            for (int r = 0; r < 4; ++r) {
                float v = acc[i][j][r] + bv;
                size_t ci = (size_t)(row0 + r) * ldc + col;
                if constexpr (OMODE == 2) ((float*)C)[ci] = v;
                else                      ((bf16_t*)C)[ci] = (bf16_t)v;
            }
        }
    }
}

// ---------- split-K combine: out = P0 + P1 + biaso, dual-dtype store ----------
__global__ void k_combine(const float* __restrict__ P, const float* __restrict__ biaso,
                          void* __restrict__ out, const void* __restrict__ mask) {
    const bool bfm = detect_bf16(mask);
    const int i = (blockIdx.x * 256 + threadIdx.x) * 4;
    const f32x4 p0 = *(const f32x4*)&P[i];
    const f32x4 p1 = *(const f32x4*)&P[i + MTOK * 1024];
    const int col = i & 1023;
#pragma unroll
    for (int j = 0; j < 4; ++j) {
        float v = p0[j] + p1[j] + biaso[col + j];
        if (bfm) ((unsigned short*)out)[i + j] = __builtin_bit_cast(unsigned short, (bf16_t)v);
        else     ((float*)out)[i + j] = v;
    }
}

// ---------- fused 4x small GEMM (low-rank effective weights), z-indexed ----------
__global__ __launch_bounds__(256)
void k_gemm_small4(const bf16_t* __restrict__ Abuf, const bf16_t* __restrict__ Bbuf,
                   bf16_t* __restrict__ Wcat, bf16_t* __restrict__ WoT) {
    __shared__ __align__(16) bf16_t A0[64 * 32], A1[64 * 32], B0[4096], B1[4096];
    const int z = blockIdx.z;
    const bf16_t* A = Abuf + (size_t)z * Hn * Rn;
    const bf16_t* B = Bbuf + (size_t)z * Hn * Rn;
    bf16_t* C = (z < 3) ? (Wcat + (size_t)z * Hn * Hn) : WoT;
    const int ldc = (z < 3) ? Hn : 2048;

    const int bm = blockIdx.x * 64, bn = blockIdx.y * 128;
    f32x4 acc[2][4];
    gemm_core_db<2>(A, Rn, B, Rn, Rn, A0, A1, B0, B1, bm, bn, acc);

    const int lane = threadIdx.x & 63;
    const int w    = threadIdx.x >> 6;
    const int wr   = (w >> 1) * 32;
    const int wc   = (w & 1) * 64;
    const int fr   = lane & 15;
    const int quad = lane >> 4;
#pragma unroll
    for (int i = 0; i < 2; ++i)
#pragma unroll
        for (int j = 0; j < 4; ++j)
#pragma unroll
            for (int r = 0; r < 4; ++r)
                C[(size_t)(bm + wr + i * 16 + quad * 4 + r) * ldc + bn + wc + j * 16 + fr]
                    = (bf16_t)acc[i][j][r];
}

// ---------- causal flash attention v6: 64-key tiles, XCD-pinned, double-buffered ----------
__global__ __launch_bounds__(256, 4)
void k_flash6(const bf16_t* __restrict__ Y, const f16_t* __restrict__ Vt_g,
              bf16_t* __restrict__ Ctx) {
    const int id   = blockIdx.x;
    const int inst = id & 63;               // p*32 + b*16 + h
    const int qt2  = 15 - (id >> 6);        // longest q-tiles dispatched first
    const int p = inst >> 5, b = (inst >> 4) & 1, h = inst & 15;

    const int tid  = threadIdx.x;
    const int lane = tid & 63;
    const int w    = tid >> 6;
    const int fr   = lane & 15;
    const int quad = lane >> 4;

    const int rowbase = b * TN;
    const int qbase   = qt2 * 128;
    const int qcol = p * 3072 + h * 64;
    const int kcol = qcol + 1024;
    const int ccol = p * 1024 + h * 64;

    __shared__ __align__(16) bf16_t Kb[2][2][64 * 32];   // [buf][dh-half][key][32]
    __shared__ __align__(16) f16_t  Vb[2][64 * 64];      // [buf] V^T chunk-swizzled

    const int r64 = tid >> 2;
    const int c8  = (tid & 3) * 8;

    size_t vsrc[2];
#pragma unroll
    for (int t = 0; t < 2; ++t) {
        int pp = w * 128 + t * 64 + lane;
        int d  = pp >> 3;
        vsrc[t] = (size_t)(inst * 64 + d) * TN + ((((pp & 7) - d) & 7) * 8);
    }

    f16x4 ones;
#pragma unroll
    for (int j = 0; j < 4; ++j) ones[j] = (f16_t)1.0f;

    bf16x8 qf[2][2];
#pragma unroll
    for (int s = 0; s < 2; ++s) {
        const size_t qrow = (size_t)(rowbase + qbase + s * 64 + w * 16 + fr) * NCAT + qcol;
        qf[s][0] = *(const bf16x8*)&Y[qrow + quad * 8];
        qf[s][1] = *(const bf16x8*)&Y[qrow + 32 + quad * 8];
    }

    f32x4 o[2][4], lacc[2];
#pragma unroll
    for (int s = 0; s < 2; ++s) {
        lacc[s] = {0.f, 0.f, 0.f, 0.f};
#pragma unroll
        for (int db = 0; db < 4; ++db) o[s][db] = {0.f, 0.f, 0.f, 0.f};
    }

    const int t0 = (quad >> 1) + (fr & 7);   // V read swizzle base
    const int h4 = (quad & 1) * 4;           // 8B half within 16B chunk

    const int kmax = 2 * qt2 + 1;

    auto stage = [&](int kt, int bsel) {
        const bf16_t* ksrc = &Y[(size_t)(rowbase + kt * 64 + r64) * NCAT + kcol + c8];
        gload16(ksrc,      &Kb[bsel][0][tid * 8]);
        gload16(ksrc + 32, &Kb[bsel][1][tid * 8]);
#pragma unroll
        for (int t = 0; t < 2; ++t)
            gload16(&Vt_g[vsrc[t] + kt * 64], &Vb[bsel][(w * 128 + t * 64 + lane) * 8]);
    };

    stage(0, 0);

    for (int kt = 0; kt <= kmax; ++kt) {
        const int cur = kt & 1;
        __syncthreads();                       // drains DMA(kt); frees buf cur^1
        if (kt < kmax) stage(kt + 1, cur ^ 1); // prefetch overlaps compute below

#pragma unroll
        for (int s = 0; s < 2; ++s) {
            const int dk = 2 * qt2 + s;
            if (kt > dk) continue;

            f32x4 sacc[4];
#pragma unroll
            for (int nb = 0; nb < 4; ++nb) {
                bf16x8 kf0 = *(const bf16x8*)&Kb[cur][0][(nb * 16 + fr) * 32 + quad * 8];
                bf16x8 kf1 = *(const bf16x8*)&Kb[cur][1][(nb * 16 + fr) * 32 + quad * 8];
                f32x4 t4 = {0.f, 0.f, 0.f, 0.f};
                t4 = __builtin_amdgcn_mfma_f32_16x16x32_bf16(kf0, qf[s][0], t4, 0, 0, 0);
                t4 = __builtin_amdgcn_mfma_f32_16x16x32_bf16(kf1, qf[s][1], t4, 0, 0, 0);
                sacc[nb] = t4;
            }
            if (kt == dk) {
                const int kl = quad * 4;
                const int ql = w * 16 + fr;
#pragma unroll
                for (int nb = 0; nb < 4; ++nb)
#pragma unroll
                    for (int r = 0; r < 4; ++r)
                        if (nb * 16 + kl + r > ql) sacc[nb][r] = -1e30f;
            }

            f16x4 pf[4];
#pragma unroll
            for (int nb = 0; nb < 4; ++nb)
#pragma unroll
                for (int r = 0; r < 4; ++r)
                    pf[nb][r] = (f16_t)__expf(sacc[nb][r] - SOFT_OFF);

#pragma unroll
            for (int nb = 0; nb < 4; ++nb)
                lacc[s] = __builtin_amdgcn_mfma_f32_16x16x16f16(pf[nb], ones, lacc[s], 0, 0, 0);

#pragma unroll
            for (int db = 0; db < 4; ++db) {
                const int vbase = (db * 16 + fr) * 64 + h4;
#pragma unroll
                for (int nb = 0; nb < 4; ++nb) {
                    f16x4 vf = *(const f16x4*)&Vb[cur][vbase + (((nb * 2 + t0) & 7) * 8)];
                    o[s][db] = __builtin_amdgcn_mfma_f32_16x16x16f16(pf[nb], vf, o[s][db], 0, 0, 0);
                }
            }
        }
    }

#pragma unroll
    for (int s = 0; s < 2; ++s)
#pragma unroll
        for (int r = 0; r < 4; ++r) {
            const float inv = 1.0f / lacc[s][r];
            const size_t trow = (size_t)(rowbase + qbase + s * 64 + w * 16 + quad * 4 + r);
#pragma unroll
            for (int db = 0; db < 4; ++db)
                Ctx[trow * 2048 + ccol + db * 16 + fr] = (bf16_t)(o[s][db][r] * inv);
        }
}

// ---------- launcher ----------
extern "C" void kernel_launch(void* const* d_in, const int* in_sizes, int n_in,
                              void* d_out, int out_size, void* d_ws, size_t ws_size,
                              hipStream_t stream) {
    const void* x    = d_in[0];
    const void* mask = d_in[1];
    const void* Vh[4] = { d_in[2],  d_in[6],  d_in[10], d_in[14] };
    const void* Sp[4] = { d_in[3],  d_in[7],  d_in[11], d_in[15] };
    const void* Up[4] = { d_in[4],  d_in[8],  d_in[12], d_in[16] };
    const void* bb[4] = { d_in[5],  d_in[9],  d_in[13], d_in[17] };
    const void* Wp[4] = { d_in[18], d_in[20], d_in[22], d_in[24] };
    const void* bf[4] = { d_in[19], d_in[21], d_in[23], d_in[25] };

    char* ws = (char*)d_ws;
    size_t off = 0;
    auto alloc = [&](size_t bytes) -> void* {
        void* p = ws + off;
        off = (off + bytes + 255) & ~(size_t)255;
        return p;
    };
    bf16_t* Xb      = (bf16_t*)alloc((size_t)MTOK * Hn * 2);       // 8 MB
    bf16_t* Wcat    = (bf16_t*)alloc((size_t)NCAT * Hn * 2);       // 12 MB  [N=6144][K=1024]
    bf16_t* Yb      = (bf16_t*)alloc((size_t)MTOK * NCAT * 2);     // 48 MB  (V cols unused)
    bf16_t* Ctx     = (bf16_t*)alloc((size_t)MTOK * 2048 * 2);     // 16 MB  [tok][lr|full]
    bf16_t* WoT     = (bf16_t*)alloc((size_t)Hn * 2048 * 2);       // 4 MB   [N=1024][K=2048]
    f16_t*  Vt_g    = (f16_t*)alloc((size_t)64 * 64 * TN * 2);     // 16 MB  [inst*64+d][key] f16
    bf16_t* Abuf    = (bf16_t*)alloc((size_t)4 * Hn * Rn * 2);
    bf16_t* Bbuf    = (bf16_t*)alloc((size_t)4 * Hn * Rn * 2);
    float*  biascat = (float*)alloc(NCAT * 4);
    float*  biaso   = (float*)alloc(Hn * 4);
    // split-K partial buffer (2 x 16 MB f32) aliased onto Yb: Yb is dead after
    // flash, and the out-proj -> combine chain is stream-ordered after it.
    float*  Psplit  = (float*)Yb;

    // 1) fused prep (x convert + lowrank factors + biases + weight transposes)
    PrepArgs pa;
    pa.x = x; pa.mask = mask;
    for (int i = 0; i < 4; ++i) {
        pa.Vh[i] = Vh[i]; pa.S[i] = Sp[i]; pa.U[i] = Up[i];
        pa.bb[i] = bb[i]; pa.bfb[i] = bf[i];
        pa.W[i] = Wp[i];
    }
    for (int i = 0; i < 3; ++i) {
        pa.Wdst[i] = Wcat + (size_t)(3 * Hn + i * Hn) * Hn;
        pa.Wldd[i] = Hn; pa.Wscale[i] = (i == 0) ? QSCALE : 1.0f;
    }
    pa.Wdst[3] = WoT + 1024; pa.Wldd[3] = 2048; pa.Wscale[3] = 0.4f;
    pa.Xb = Xb; pa.Abuf = Abuf; pa.Bbuf = Bbuf; pa.biascat = biascat; pa.biaso = biaso;
    k_prep<<<12316, 256, 0, stream>>>(pa);

    // 2) low-rank effective weights: Wlr^T = (U*S) @ Vh^T
    k_gemm_small4<<<dim3(16, 8, 4), 256, 0, stream>>>(Abuf, Bbuf, Wcat, WoT);

    // 3) fused QKV (both paths): Y = x @ Wcat^T + biascat; V-blocks -> Vt_g (f16)
    k_gemm<4, 0, true, 1><<<1536, 256, 0, stream>>>(
        Xb, Hn, Wcat, Hn, Yb, NCAT, Hn, biascat, Vt_g);

    // 4) causal flash attention, both paths (XCD-pinned 1D grid)
    k_flash6<<<1024, 256, 0, stream>>>(Yb, Vt_g, Ctx);

    // 5) out-proj split-K x2 (128x128 tiles, 512 blocks = 2/CU), f32 partials
    k_gemm<4, 2, false, 3><<<512, 256, 0, stream>>>(
        Ctx, 2048, WoT, 2048, Psplit, 1024, 1024, nullptr, nullptr);

    // 6) combine halves + bias + ALPHA-blended dual-dtype store
    k_combine<<<4096, 256, 0, stream>>>(Psplit, biaso, d_out, mask);
}